// Round 1
// baseline (4409.854 us; speedup 1.0000x reference)
//
#include <hip/hip_runtime.h>
#include <hip/hip_bf16.h>

#define NN      2048
#define NSTEPS  2047
#define NPAIRS  1024
#define MROWS   8192

typedef __attribute__((ext_vector_type(8))) __bf16 bf16x8;
typedef __attribute__((ext_vector_type(4))) float  f32x4;

__device__ __forceinline__ unsigned short f2bf(float f) {
  unsigned int u = __float_as_uint(f);
  u += 0x7fffu + ((u >> 16) & 1u);   // RNE
  return (unsigned short)(u >> 16);
}

__device__ __forceinline__ void gload_lds16(const unsigned short* g, unsigned short* l) {
  __builtin_amdgcn_global_load_lds((const __attribute__((address_space(1))) void*)g,
                                   (__attribute__((address_space(3))) void*)l, 16, 0, 0);
}

// ---- kernel 1: angles -> (cos,sin); blocks(int32) -> packed (i | j<<16)
__global__ __launch_bounds__(256) void prep_kernel(
    const float* __restrict__ angles, const int* __restrict__ blocks,
    float2* __restrict__ cs, unsigned int* __restrict__ ij) {
  int idx = blockIdx.x * 256 + threadIdx.x;
  if (idx >= NSTEPS * NPAIRS) return;
  float s, c;
  sincosf(angles[idx], &s, &c);
  cs[idx] = make_float2(c, s);
  unsigned int i = (unsigned int)blocks[2 * idx];
  unsigned int j = (unsigned int)blocks[2 * idx + 1];
  ij[idx] = i | (j << 16);
}

// ---- kernel 2: x fp32 -> bf16 (vectorized)
__global__ __launch_bounds__(256) void cvt_kernel(
    const float4* __restrict__ x, ushort4* __restrict__ xb, int n4) {
  int idx = blockIdx.x * 256 + threadIdx.x;
  if (idx >= n4) return;
  float4 v = x[idx];
  ushort4 o;
  o.x = f2bf(v.x); o.y = f2bf(v.y); o.z = f2bf(v.z); o.w = f2bf(v.w);
  xb[idx] = o;
}

// ---- kernel 3: build U. Each WG owns 8 rows of U in LDS (transposed [col][row]),
// applies all 2047 rotation blocks locally (rows are independent under column ops).
__global__ __launch_bounds__(512) void build_kernel(
    const float2* __restrict__ cs, const unsigned int* __restrict__ ij,
    unsigned short* __restrict__ Ub) {
  __shared__ float rows[NN * 8];          // 64 KB, layout rows[col*8 + r]
  const int tid = threadIdx.x;
  const int wg  = blockIdx.x;             // owns U rows wg*8 .. wg*8+7

  for (int idx = tid; idx < NN * 8; idx += 512) {
    int i = idx >> 3, r = idx & 7;
    rows[idx] = (i == (wg * 8 + r)) ? 1.0f : 0.0f;
  }
  __syncthreads();

  const int p0 = tid >> 3;                // base pair index (0..63)
  const int r  = tid & 7;                 // which of the 8 rows
  for (int t = 0; t < NSTEPS; ++t) {
    const float2*       cst = cs + t * NPAIRS;
    const unsigned int* ijt = ij + t * NPAIRS;
#pragma unroll 4
    for (int k = 0; k < 16; ++k) {        // 64 pairs per k-chunk x 8 rows = 512 threads
      int p = p0 + (k << 6);
      unsigned int pr = ijt[p];
      int i = (int)(pr & 0xffffu);
      int j = (int)(pr >> 16);
      float2 csv = cst[p];
      float vi = rows[(i << 3) + r];
      float vj = rows[(j << 3) + r];
      rows[(i << 3) + r] = fmaf(csv.x, vi,  csv.y * vj);
      rows[(j << 3) + r] = fmaf(csv.x, vj, -csv.y * vi);
    }
    __syncthreads();
  }

  // write out as bf16, row-major U[o][i]; consecutive tid -> consecutive i (coalesced)
  for (int idx = tid; idx < NN * 8; idx += 512) {
    int i  = idx & (NN - 1);
    int rr = idx >> 11;
    Ub[(size_t)(wg * 8 + rr) * NN + i] = f2bf(rows[(i << 3) + rr]);
  }
}

// ---- kernel 4: C = A * B^T + bias.  A = x_bf16 [8192][2048], B = U_bf16 [2048][2048]
// m97-style 128x128 tile, BK=32, 4 waves (2x2), 4x4 16x16x32 frags per wave.
#define BM 128
#define BN 128
#define BK 32

__global__ __launch_bounds__(256) void gemm_kernel(
    const unsigned short* __restrict__ A, const unsigned short* __restrict__ B,
    const float* __restrict__ bias, float* __restrict__ C) {
  __shared__ unsigned short As[BM * BK];  // 8 KB, row-major [row][k]
  __shared__ unsigned short Bs[BN * BK];  // 8 KB
  const int tid  = threadIdx.x;
  const int lane = tid & 63;
  const int wave = tid >> 6;
  const int bm = blockIdx.x, bn = blockIdx.y;
  const int wm = wave & 1, wn = wave >> 1;

  // staging geometry: per wave, 2 issues of 64 lanes x 16B; LDS dest is wave-uniform base
  const int srow = wave * 16 + (lane >> 2);      // +64 for it=1
  const int scol = (lane & 3) * 8;
  const unsigned short* Ag = A + (size_t)(bm * BM + srow) * NN + scol;
  const unsigned short* Bg = B + (size_t)(bn * BN + srow) * NN + scol;

  const int fm = lane & 15;
  const int kb = lane >> 4;

  f32x4 acc[4][4];
#pragma unroll
  for (int a_ = 0; a_ < 4; ++a_)
#pragma unroll
    for (int b_ = 0; b_ < 4; ++b_) acc[a_][b_] = (f32x4){0.f, 0.f, 0.f, 0.f};

  for (int kt = 0; kt < NN / BK; ++kt) {
    const int k0 = kt * BK;
#pragma unroll
    for (int it = 0; it < 2; ++it) {
      gload_lds16(Ag + (size_t)(it * 64) * NN + k0, &As[wave * 512 + it * 2048]);
      gload_lds16(Bg + (size_t)(it * 64) * NN + k0, &Bs[wave * 512 + it * 2048]);
    }
    __syncthreads();   // compiler drains vmcnt before s_barrier

    bf16x8 af[4], bfr[4];
#pragma unroll
    for (int a_ = 0; a_ < 4; ++a_)
      af[a_] = *(const bf16x8*)&As[(wm * 64 + a_ * 16 + fm) * BK + kb * 8];
#pragma unroll
    for (int b_ = 0; b_ < 4; ++b_)
      bfr[b_] = *(const bf16x8*)&Bs[(wn * 64 + b_ * 16 + fm) * BK + kb * 8];
#pragma unroll
    for (int a_ = 0; a_ < 4; ++a_)
#pragma unroll
      for (int b_ = 0; b_ < 4; ++b_)
        acc[a_][b_] = __builtin_amdgcn_mfma_f32_16x16x32_bf16(af[a_], bfr[b_], acc[a_][b_], 0, 0, 0);
    __syncthreads();
  }

  // epilogue: C/D layout col=lane&15, row=(lane>>4)*4+reg  [m89-verified]
  const int row_in = (lane >> 4) * 4;
#pragma unroll
  for (int a_ = 0; a_ < 4; ++a_) {
#pragma unroll
    for (int b_ = 0; b_ < 4; ++b_) {
      int gn = bn * BN + wn * 64 + b_ * 16 + fm;
      float bv = bias[gn];
#pragma unroll
      for (int v = 0; v < 4; ++v) {
        int gm = bm * BM + wm * 64 + a_ * 16 + row_in + v;
        C[(size_t)gm * NN + gn] = acc[a_][b_][v] + bv;
      }
    }
  }
}

extern "C" void kernel_launch(void* const* d_in, const int* in_sizes, int n_in,
                              void* d_out, int out_size, void* d_ws, size_t ws_size,
                              hipStream_t stream) {
  const float* x      = (const float*)d_in[0];
  const float* angles = (const float*)d_in[1];
  const float* bias   = (const float*)d_in[2];
  const int*   blocks = (const int*)d_in[3];
  float* out = (float*)d_out;

  char* ws = (char*)d_ws;
  float2*         cs = (float2*)ws;                                   // 16,769,024 B
  unsigned int*   ij = (unsigned int*)(ws + 16769024);                //  8,384,512 B
  unsigned short* xb = (unsigned short*)(ws + 25153536);              // 33,554,432 B
  unsigned short* Ub = (unsigned short*)(ws + 58707968);              //  8,388,608 B
  // total 67,096,576 B

  prep_kernel<<<dim3(8188), dim3(256), 0, stream>>>(angles, blocks, cs, ij);
  cvt_kernel<<<dim3(16384), dim3(256), 0, stream>>>((const float4*)x, (ushort4*)xb,
                                                    MROWS * NN / 4);
  build_kernel<<<dim3(256), dim3(512), 0, stream>>>(cs, ij, Ub);
  gemm_kernel<<<dim3(MROWS / BM, NN / BN), dim3(256), 0, stream>>>(xb, Ub, bias, out);
}

// Round 2
// 1905.932 us; speedup vs baseline: 2.3138x; 2.3138x over previous
//
#include <hip/hip_runtime.h>
#include <hip/hip_bf16.h>

#define NN      2048
#define NSTEPS  2047
#define NPAIRS  1024
#define MROWS   8192

typedef __attribute__((ext_vector_type(8))) __bf16 bf16x8;
typedef __attribute__((ext_vector_type(4))) float  f32x4;

__device__ __forceinline__ unsigned short f2bf(float f) {
  unsigned int u = __float_as_uint(f);
  u += 0x7fffu + ((u >> 16) & 1u);   // RNE
  return (unsigned short)(u >> 16);
}

__device__ __forceinline__ void gload_lds16(const unsigned short* g, unsigned short* l) {
  __builtin_amdgcn_global_load_lds((const __attribute__((address_space(1))) void*)g,
                                   (__attribute__((address_space(3))) void*)l, 16, 0, 0);
}

// ---- kernel 1: angles -> (cos,sin). No ij table needed anymore (static pairing in position space).
__global__ __launch_bounds__(256) void prep_kernel(
    const float* __restrict__ angles, float2* __restrict__ cs) {
  int idx = blockIdx.x * 256 + threadIdx.x;
  if (idx >= NSTEPS * NPAIRS) return;
  float s, c;
  sincosf(angles[idx], &s, &c);
  cs[idx] = make_float2(c, s);
}

// ---- kernel 2: x fp32 -> bf16 (vectorized)
__global__ __launch_bounds__(256) void cvt_kernel(
    const float4* __restrict__ x, ushort4* __restrict__ xb, int n4) {
  int idx = blockIdx.x * 256 + threadIdx.x;
  if (idx >= n4) return;
  float4 v = x[idx];
  ushort4 o;
  o.x = f2bf(v.x); o.y = f2bf(v.y); o.z = f2bf(v.z); o.w = f2bf(v.w);
  xb[idx] = o;
}

// ---- kernel 3: register-systolic build of U.
// Position space: pairing is STATIC (pair k = (pos k, pos 2047-k)); values shift
// along one 2047-cycle conveyor each step (pos 0 stationary). Lane l owns pairs
// 16l..16l+15: rotation is lane-local; shift = 1 shfl_up + 1 shfl_down per row.
// Register index rotation handled by 16-step unroll (phase = t mod 16).
// Each wave carries 2 rows (F0/S0, F1/S1); 1024 waves total; no LDS, no barriers.
__global__ __launch_bounds__(256, 1) void build_kernel(
    const float4* __restrict__ cs4, unsigned short* __restrict__ Ub) {
  const int lane = threadIdx.x & 63;
  const int w    = blockIdx.x * 4 + (threadIdx.x >> 6);   // wave id 0..1023
  const int rA = 2 * w, rB = 2 * w + 1;
  const bool l0 = (lane == 0), l63 = (lane == 63);

  float F0[16], S0[16], F1[16], S1[16];
#pragma unroll
  for (int e = 0; e < 16; ++e) {
    const int pk = (lane << 4) + e;          // F pos = pk ; S pos = 2047-pk
    F0[e] = (pk == rA) ? 1.f : 0.f;
    S0[e] = ((2047 - pk) == rA) ? 1.f : 0.f;
    F1[e] = (pk == rB) ? 1.f : 0.f;
    S1[e] = ((2047 - pk) == rB) ? 1.f : 0.f;
  }

  const float4* csl = cs4 + (lane << 3);     // lane's 8 float4 (16 pairs) within a slice
  float4 csA[8], csB[8];
#pragma unroll
  for (int j = 0; j < 8; ++j) csA[j] = csl[j];   // slice 0

#define PREF(NXT, TNEXT) { const float4* p_ = csl + (size_t)(TNEXT) * 512; \
  _Pragma("unroll") for (int j_ = 0; j_ < 8; ++j_) NXT[j_] = p_[j_]; }

  // reg mapping at step T (PHI = T&15): F elem e in F[(e-T)&15]; S elem e in S[(e+T)&15]
#define ROTROW(F, S, PHI, CUR) \
  _Pragma("unroll") for (int e_ = 0; e_ < 16; ++e_) { \
    const int rF_ = (e_ - (PHI)) & 15, rS_ = (e_ + (PHI)) & 15; \
    const float c_ = (e_ & 1) ? CUR[e_ >> 1].z : CUR[e_ >> 1].x; \
    const float s_ = (e_ & 1) ? CUR[e_ >> 1].w : CUR[e_ >> 1].y; \
    const float vi_ = F[rF_], vj_ = S[rS_]; \
    F[rF_] = fmaf(c_, vi_, s_ * vj_); \
    S[rS_] = fmaf(c_, vj_, -(s_ * vi_)); \
  }

  // conveyor: F flows +1 (lane-increasing), S flows -1; pos0 stationary;
  // lane0: new F(e=1 slot) <- old S(e=0);  lane63: new S(e=15 slot) <- old F(e=15)
#define SHIFTROW(F, S, PHI) { \
    const int pF_ = (15 - (PHI)) & 15, pT_ = (16 - (PHI)) & 15; \
    const float Fout_ = F[pF_], Sout_ = S[(PHI)], Stat_ = F[pT_]; \
    const float fin_ = __shfl_up(Fout_, 1); \
    const float sdn_ = __shfl_down(Sout_, 1); \
    F[pF_]   = l0  ? Stat_ : fin_; \
    S[(PHI)] = l63 ? Fout_ : sdn_; \
    F[pT_]   = l0  ? Sout_ : F[pT_]; \
  }

#define STEP(PHI, CUR, NXT, TB) { \
    PREF(NXT, (TB) + (PHI) + 1); \
    ROTROW(F0, S0, PHI, CUR) ROTROW(F1, S1, PHI, CUR) \
    SHIFTROW(F0, S0, PHI) SHIFTROW(F1, S1, PHI) }

  int tb = 0;
#pragma unroll 1
  for (int it = 0; it < 127; ++it, tb += 16) {
    STEP(0,  csA, csB, tb) STEP(1,  csB, csA, tb)
    STEP(2,  csA, csB, tb) STEP(3,  csB, csA, tb)
    STEP(4,  csA, csB, tb) STEP(5,  csB, csA, tb)
    STEP(6,  csA, csB, tb) STEP(7,  csB, csA, tb)
    STEP(8,  csA, csB, tb) STEP(9,  csB, csA, tb)
    STEP(10, csA, csB, tb) STEP(11, csB, csA, tb)
    STEP(12, csA, csB, tb) STEP(13, csB, csA, tb)
    STEP(14, csA, csB, tb) STEP(15, csB, csA, tb)
  }
  // tail: t = 2032..2046 (15 steps); prefetches reach padded slice 2047 (unused)
  STEP(0,  csA, csB, 2032) STEP(1,  csB, csA, 2032)
  STEP(2,  csA, csB, 2032) STEP(3,  csB, csA, 2032)
  STEP(4,  csA, csB, 2032) STEP(5,  csB, csA, 2032)
  STEP(6,  csA, csB, 2032) STEP(7,  csB, csA, 2032)
  STEP(8,  csA, csB, 2032) STEP(9,  csB, csA, 2032)
  STEP(10, csA, csB, 2032) STEP(11, csB, csA, 2032)
  STEP(12, csA, csB, 2032) STEP(13, csB, csA, 2032)
  STEP(14, csA, csB, 2032)

  // Readout at T=2047: positions == labels (2047-cycle closed).
  // F: col 16l+e lives in F[(e+1)&15].  S: col 2047-(16l+e) in S[(e-1)&15].
#define WRITEROW(F, S, ROW) { \
    unsigned short* rowp = Ub + (size_t)(ROW) * NN; \
    unsigned int uf[8], us[8]; \
    _Pragma("unroll") for (int j_ = 0; j_ < 8; ++j_) { \
      uf[j_] = (unsigned)f2bf(F[(2*j_ + 1) & 15]) | ((unsigned)f2bf(F[(2*j_ + 2) & 15]) << 16); \
      us[j_] = (unsigned)f2bf(S[(14 - 2*j_) & 15]) | ((unsigned)f2bf(S[(13 - 2*j_) & 15]) << 16); \
    } \
    uint4* pF_ = (uint4*)(rowp + (lane << 4)); \
    pF_[0] = make_uint4(uf[0], uf[1], uf[2], uf[3]); \
    pF_[1] = make_uint4(uf[4], uf[5], uf[6], uf[7]); \
    uint4* pS_ = (uint4*)(rowp + (2032 - (lane << 4))); \
    pS_[0] = make_uint4(us[0], us[1], us[2], us[3]); \
    pS_[1] = make_uint4(us[4], us[5], us[6], us[7]); \
  }

  WRITEROW(F0, S0, rA)
  WRITEROW(F1, S1, rB)
}

// ---- kernel 4: C = A * B^T + bias.  A = x_bf16 [8192][2048], B = U_bf16 [2048][2048]
#define BM 128
#define BN 128
#define BK 32

__global__ __launch_bounds__(256) void gemm_kernel(
    const unsigned short* __restrict__ A, const unsigned short* __restrict__ B,
    const float* __restrict__ bias, float* __restrict__ C) {
  __shared__ unsigned short As[BM * BK];
  __shared__ unsigned short Bs[BN * BK];
  const int tid  = threadIdx.x;
  const int lane = tid & 63;
  const int wave = tid >> 6;
  const int bm = blockIdx.x, bn = blockIdx.y;
  const int wm = wave & 1, wn = wave >> 1;

  const int srow = wave * 16 + (lane >> 2);
  const int scol = (lane & 3) * 8;
  const unsigned short* Ag = A + (size_t)(bm * BM + srow) * NN + scol;
  const unsigned short* Bg = B + (size_t)(bn * BN + srow) * NN + scol;

  const int fm = lane & 15;
  const int kb = lane >> 4;

  f32x4 acc[4][4];
#pragma unroll
  for (int a_ = 0; a_ < 4; ++a_)
#pragma unroll
    for (int b_ = 0; b_ < 4; ++b_) acc[a_][b_] = (f32x4){0.f, 0.f, 0.f, 0.f};

  for (int kt = 0; kt < NN / BK; ++kt) {
    const int k0 = kt * BK;
#pragma unroll
    for (int it = 0; it < 2; ++it) {
      gload_lds16(Ag + (size_t)(it * 64) * NN + k0, &As[wave * 512 + it * 2048]);
      gload_lds16(Bg + (size_t)(it * 64) * NN + k0, &Bs[wave * 512 + it * 2048]);
    }
    __syncthreads();

    bf16x8 af[4], bfr[4];
#pragma unroll
    for (int a_ = 0; a_ < 4; ++a_)
      af[a_] = *(const bf16x8*)&As[(wm * 64 + a_ * 16 + fm) * BK + kb * 8];
#pragma unroll
    for (int b_ = 0; b_ < 4; ++b_)
      bfr[b_] = *(const bf16x8*)&Bs[(wn * 64 + b_ * 16 + fm) * BK + kb * 8];
#pragma unroll
    for (int a_ = 0; a_ < 4; ++a_)
#pragma unroll
      for (int b_ = 0; b_ < 4; ++b_)
        acc[a_][b_] = __builtin_amdgcn_mfma_f32_16x16x32_bf16(af[a_], bfr[b_], acc[a_][b_], 0, 0, 0);
    __syncthreads();
  }

  const int row_in = (lane >> 4) * 4;
#pragma unroll
  for (int a_ = 0; a_ < 4; ++a_) {
#pragma unroll
    for (int b_ = 0; b_ < 4; ++b_) {
      int gn = bn * BN + wn * 64 + b_ * 16 + fm;
      float bv = bias[gn];
#pragma unroll
      for (int v = 0; v < 4; ++v) {
        int gm = bm * BM + wm * 64 + a_ * 16 + row_in + v;
        C[(size_t)gm * NN + gn] = acc[a_][b_][v] + bv;
      }
    }
  }
}

extern "C" void kernel_launch(void* const* d_in, const int* in_sizes, int n_in,
                              void* d_out, int out_size, void* d_ws, size_t ws_size,
                              hipStream_t stream) {
  const float* x      = (const float*)d_in[0];
  const float* angles = (const float*)d_in[1];
  const float* bias   = (const float*)d_in[2];
  float* out = (float*)d_out;

  char* ws = (char*)d_ws;
  float2*         cs = (float2*)ws;                        // 2048 slices * 8KB = 16,777,216 B (slice 2047 = pad)
  unsigned short* xb = (unsigned short*)(ws + 16777216);   // 33,554,432 B
  unsigned short* Ub = (unsigned short*)(ws + 50331648);   //  8,388,608 B
  // total 58,720,256 B

  prep_kernel<<<dim3(8188), dim3(256), 0, stream>>>(angles, cs);
  cvt_kernel<<<dim3(16384), dim3(256), 0, stream>>>((const float4*)x, (ushort4*)xb,
                                                    MROWS * NN / 4);
  build_kernel<<<dim3(256), dim3(256), 0, stream>>>((const float4*)cs, Ub);
  gemm_kernel<<<dim3(MROWS / BM, NN / BN), dim3(256), 0, stream>>>(xb, Ub, bias, out);
}

// Round 3
// 1191.479 us; speedup vs baseline: 3.7012x; 1.5996x over previous
//
#include <hip/hip_runtime.h>
#include <hip/hip_bf16.h>

#define NN      2048
#define NSTEPS  2047
#define NPAIRS  1024
#define MROWS   8192

typedef __attribute__((ext_vector_type(8))) __bf16 bf16x8;
typedef __attribute__((ext_vector_type(4))) float  f32x4;
typedef __attribute__((ext_vector_type(2))) float  f32x2;

__device__ __forceinline__ unsigned short f2bf(float f) {
  unsigned int u = __float_as_uint(f);
  u += 0x7fffu + ((u >> 16) & 1u);   // RNE
  return (unsigned short)(u >> 16);
}

__device__ __forceinline__ void gload_lds16(const void* g, void* l) {
  __builtin_amdgcn_global_load_lds((const __attribute__((address_space(1))) void*)g,
                                   (__attribute__((address_space(3))) void*)l, 16, 0, 0);
}

// ---- kernel 1: angles -> (cos,sin) table, layout cs[step][pair] (8 KB/step slice)
__global__ __launch_bounds__(256) void prep_kernel(
    const float* __restrict__ angles, float2* __restrict__ cs) {
  int idx = blockIdx.x * 256 + threadIdx.x;
  if (idx >= NSTEPS * NPAIRS) return;
  float s, c;
  sincosf(angles[idx], &s, &c);
  cs[idx] = make_float2(c, s);
}

// ---- kernel 2: x fp32 -> bf16 (vectorized)
__global__ __launch_bounds__(256) void cvt_kernel(
    const float4* __restrict__ x, ushort4* __restrict__ xb, int n4) {
  int idx = blockIdx.x * 256 + threadIdx.x;
  if (idx >= n4) return;
  float4 v = x[idx];
  ushort4 o;
  o.x = f2bf(v.x); o.y = f2bf(v.y); o.z = f2bf(v.z); o.w = f2bf(v.w);
  xb[idx] = o;
}

// ---- kernel 3: register-systolic build of U (position space, static pairing).
// WG = 4 waves = (h: pair-half 0/1) x (rp: row-pair 0/1); WG owns rows 4g..4g+3.
// Wave (h,rp) holds pairs [512h, 512h+512) for rows {4g+2rp, 4g+2rp+1} as f32x2.
// 8 pairs/lane, period-8 register-phase unroll. cs slice staged to LDS once per WG
// (double-buffered, XOR-swizzled), inter-wave conveyor boundary via 4 LDS floats.
__global__ __launch_bounds__(256, 2) void build_kernel(
    const char* __restrict__ csb, unsigned short* __restrict__ Ub) {
  __shared__ char  lds_cs[2][8192];
  __shared__ float exch[2][2][4];   // [parity][rp][{Fout.x,Fout.y,Sout.x,Sout.y}]

  const int tid  = threadIdx.x;
  const int lane = tid & 63;
  const int wv   = tid >> 6;
  const int h    = wv & 1;          // pair-half
  const int rp   = wv >> 1;         // row-pair
  const int r0   = blockIdx.x * 4 + 2 * rp;   // rows r0, r0+1
  const bool l0 = (lane == 0), l63 = (lane == 63);

  // state: F elem e <-> pair p = 512h + 8l + e (pos p); S elem e <-> pos 2047-p
  f32x2 FF[8], SS[8];
#pragma unroll
  for (int e = 0; e < 8; ++e) {
    const int p = 512 * h + 8 * lane + e;
    FF[e] = (f32x2){(p == r0) ? 1.f : 0.f, (p == r0 + 1) ? 1.f : 0.f};
    SS[e] = (f32x2){((2047 - p) == r0) ? 1.f : 0.f, ((2047 - p) == r0 + 1) ? 1.f : 0.f};
  }

  // swizzled LDS read offsets (4x float4 per lane per step), involution L^(16*((L>>7)&7))
  unsigned int aoff[4];
  {
    const unsigned int swz = 16u * (((unsigned)lane >> 1) & 7u);
    const unsigned int base = 4096u * h + 64u * lane;
#pragma unroll
    for (int j = 0; j < 4; ++j) aoff[j] = (base | (16u * j)) ^ swz;
  }

  // staging: 8 issues of 1KB per slice; wave wv does issues 2wv, 2wv+1.
  // linear LDS dest + pre-swizzled global source: src = 1024*i + 16*(l ^ (l>>3))
  const unsigned int sl = 16u * ((unsigned)lane ^ ((unsigned)lane >> 3));
  const char* gp0 = csb + 1024 * (2 * wv)     + sl;
  const char* gp1 = csb + 1024 * (2 * wv + 1) + sl;

  // prologue: stage slice 0 into buf[0]
  gload_lds16(gp0, &lds_cs[0][2048 * wv]);
  gload_lds16(gp1, &lds_cs[0][2048 * wv + 1024]);
  gp0 += 8192; gp1 += 8192;
  __syncthreads();

#define ROT(PHI) { \
  _Pragma("unroll") for (int e_ = 0; e_ < 8; ++e_) { \
    const int rF_ = (e_ - (PHI)) & 7, rS_ = (e_ + (PHI)) & 7; \
    const float c_ = (e_ & 1) ? cv[e_ >> 1].z : cv[e_ >> 1].x; \
    const float s_ = (e_ & 1) ? cv[e_ >> 1].w : cv[e_ >> 1].y; \
    const f32x2 c2_ = {c_, c_}, s2_ = {s_, s_}; \
    const f32x2 vi_ = FF[rF_], vj_ = SS[rS_]; \
    FF[rF_] = c2_ * vi_ + s2_ * vj_; \
    SS[rS_] = c2_ * vj_ - s2_ * vi_; \
  } }

#define STEP(PHI, PAR, NPAR) { \
    float4 cv[4]; \
    _Pragma("unroll") for (int j_ = 0; j_ < 4; ++j_) \
      cv[j_] = *(const float4*)&lds_cs[PAR][aoff[j_]]; \
    ROT(PHI) \
    const int pF_ = (7 - (PHI)) & 7, pT_ = (8 - (PHI)) & 7; \
    const f32x2 Fout_ = FF[pF_], Sout_ = SS[(PHI)], Stat_ = FF[pT_]; \
    if (h == 0) { if (l63) { exch[PAR][rp][0] = Fout_.x; exch[PAR][rp][1] = Fout_.y; } } \
    else        { if (l0)  { exch[PAR][rp][2] = Sout_.x; exch[PAR][rp][3] = Sout_.y; } } \
    gload_lds16(gp0, &lds_cs[NPAR][2048 * wv]); \
    gload_lds16(gp1, &lds_cs[NPAR][2048 * wv + 1024]); \
    gp0 += 8192; gp1 += 8192; \
    __syncthreads(); \
    const float4 ex_ = *(const float4*)exch[PAR][rp]; \
    const f32x2 exA_ = {ex_.x, ex_.y}, exB_ = {ex_.z, ex_.w}; \
    f32x2 fin_, sdn_; \
    fin_.x = __shfl_up(Fout_.x, 1);   fin_.y = __shfl_up(Fout_.y, 1); \
    sdn_.x = __shfl_down(Sout_.x, 1); sdn_.y = __shfl_down(Sout_.y, 1); \
    FF[pF_]   = l0  ? (h ? exA_ : Stat_) : fin_; \
    SS[(PHI)] = l63 ? (h ? Fout_ : exB_) : sdn_; \
    FF[pT_]   = (l0 && h == 0) ? Sout_ : FF[pT_]; \
  }

#pragma unroll 1
  for (int it = 0; it < 255; ++it) {
    STEP(0, 0, 1) STEP(1, 1, 0) STEP(2, 0, 1) STEP(3, 1, 0)
    STEP(4, 0, 1) STEP(5, 1, 0) STEP(6, 0, 1) STEP(7, 1, 0)
  }
  // tail: t = 2040..2046 (staging reads padded slice 2047)
  STEP(0, 0, 1) STEP(1, 1, 0) STEP(2, 0, 1) STEP(3, 1, 0)
  STEP(4, 0, 1) STEP(5, 1, 0) STEP(6, 0, 1)

  // Readout at T=2047 (cycle closed; 2047 = -1 mod 8):
  // F elem e in reg (e+1)&7, col 512h+8l+e ; S elem e in reg (e-1)&7, col 2047-(512h+8l+e)
#pragma unroll
  for (int rr = 0; rr < 2; ++rr) {
    unsigned short* rowp = Ub + (size_t)(r0 + rr) * NN;
    unsigned int uf[4], us[4];
#pragma unroll
    for (int j = 0; j < 4; ++j) {
      const float f0 = rr ? FF[(2*j + 1) & 7].y : FF[(2*j + 1) & 7].x;
      const float f1 = rr ? FF[(2*j + 2) & 7].y : FF[(2*j + 2) & 7].x;
      const float s0 = rr ? SS[(6 - 2*j) & 7].y : SS[(6 - 2*j) & 7].x;
      const float s1 = rr ? SS[(5 - 2*j) & 7].y : SS[(5 - 2*j) & 7].x;
      uf[j] = (unsigned)f2bf(f0) | ((unsigned)f2bf(f1) << 16);
      us[j] = (unsigned)f2bf(s0) | ((unsigned)f2bf(s1) << 16);
    }
    *(uint4*)(rowp + 512 * h + 8 * lane)          = make_uint4(uf[0], uf[1], uf[2], uf[3]);
    *(uint4*)(rowp + 2040 - 512 * h - 8 * lane)   = make_uint4(us[0], us[1], us[2], us[3]);
  }
}

// ---- kernel 4: C = A * B^T + bias.  A = x_bf16 [8192][2048], B = U_bf16 [2048][2048]
#define BM 128
#define BN 128
#define BK 32

__global__ __launch_bounds__(256) void gemm_kernel(
    const unsigned short* __restrict__ A, const unsigned short* __restrict__ B,
    const float* __restrict__ bias, float* __restrict__ C) {
  __shared__ unsigned short As[BM * BK];
  __shared__ unsigned short Bs[BN * BK];
  const int tid  = threadIdx.x;
  const int lane = tid & 63;
  const int wave = tid >> 6;
  const int bm = blockIdx.x, bn = blockIdx.y;
  const int wm = wave & 1, wn = wave >> 1;

  const int srow = wave * 16 + (lane >> 2);
  const int scol = (lane & 3) * 8;
  const unsigned short* Ag = A + (size_t)(bm * BM + srow) * NN + scol;
  const unsigned short* Bg = B + (size_t)(bn * BN + srow) * NN + scol;

  const int fm = lane & 15;
  const int kb = lane >> 4;

  f32x4 acc[4][4];
#pragma unroll
  for (int a_ = 0; a_ < 4; ++a_)
#pragma unroll
    for (int b_ = 0; b_ < 4; ++b_) acc[a_][b_] = (f32x4){0.f, 0.f, 0.f, 0.f};

  for (int kt = 0; kt < NN / BK; ++kt) {
    const int k0 = kt * BK;
#pragma unroll
    for (int it = 0; it < 2; ++it) {
      gload_lds16(Ag + (size_t)(it * 64) * NN + k0, &As[wave * 512 + it * 2048]);
      gload_lds16(Bg + (size_t)(it * 64) * NN + k0, &Bs[wave * 512 + it * 2048]);
    }
    __syncthreads();

    bf16x8 af[4], bfr[4];
#pragma unroll
    for (int a_ = 0; a_ < 4; ++a_)
      af[a_] = *(const bf16x8*)&As[(wm * 64 + a_ * 16 + fm) * BK + kb * 8];
#pragma unroll
    for (int b_ = 0; b_ < 4; ++b_)
      bfr[b_] = *(const bf16x8*)&Bs[(wn * 64 + b_ * 16 + fm) * BK + kb * 8];
#pragma unroll
    for (int a_ = 0; a_ < 4; ++a_)
#pragma unroll
      for (int b_ = 0; b_ < 4; ++b_)
        acc[a_][b_] = __builtin_amdgcn_mfma_f32_16x16x32_bf16(af[a_], bfr[b_], acc[a_][b_], 0, 0, 0);
    __syncthreads();
  }

  const int row_in = (lane >> 4) * 4;
#pragma unroll
  for (int a_ = 0; a_ < 4; ++a_) {
#pragma unroll
    for (int b_ = 0; b_ < 4; ++b_) {
      int gn = bn * BN + wn * 64 + b_ * 16 + fm;
      float bv = bias[gn];
#pragma unroll
      for (int v = 0; v < 4; ++v) {
        int gm = bm * BM + wm * 64 + a_ * 16 + row_in + v;
        C[(size_t)gm * NN + gn] = acc[a_][b_][v] + bv;
      }
    }
  }
}

extern "C" void kernel_launch(void* const* d_in, const int* in_sizes, int n_in,
                              void* d_out, int out_size, void* d_ws, size_t ws_size,
                              hipStream_t stream) {
  const float* x      = (const float*)d_in[0];
  const float* angles = (const float*)d_in[1];
  const float* bias   = (const float*)d_in[2];
  float* out = (float*)d_out;

  char* ws = (char*)d_ws;
  char*           cs = ws;                                 // 2048 slices * 8KB = 16,777,216 B (slice 2047 = pad)
  unsigned short* xb = (unsigned short*)(ws + 16777216);   // 33,554,432 B
  unsigned short* Ub = (unsigned short*)(ws + 50331648);   //  8,388,608 B
  // total 58,720,256 B

  prep_kernel<<<dim3(8188), dim3(256), 0, stream>>>(angles, (float2*)cs);
  cvt_kernel<<<dim3(16384), dim3(256), 0, stream>>>((const float4*)x, (ushort4*)xb,
                                                    MROWS * NN / 4);
  build_kernel<<<dim3(512), dim3(256), 0, stream>>>(cs, Ub);
  gemm_kernel<<<dim3(MROWS / BM, NN / BN), dim3(256), 0, stream>>>(xb, Ub, bias, out);
}